// Round 3
// baseline (333.272 us; speedup 1.0000x reference)
//
#include <hip/hip_runtime.h>

// AirFitMultiHeadDNN — R3.
// R1/R2 post-mortem: compiler demoted ALL preloaded input rows (VGPR_Count=32)
// and rematerialized the global loads per use -> 2x FETCH_SIZE (strided
// re-touch misses L1/L2; working set/XCD ~20MB >> 4MB L2) and 3x VALU
// (recomputed addressing). launch_bounds alone didn't stop it.
// Fix: PIN() = empty asm with "+v" constraint on every loaded scalar.
// After the pin the VGPR is the only legal source of the value — the
// compiler cannot re-load or re-derive it. All 20 row-loads issue
// back-to-back (full L1 line reuse across the 80/240B-strided lanes),
// then 80 pinned values are consumed by the fully-unrolled head loop.
// Weights stay wave-uniform -> s_load/SGPR (SGPR=112 confirmed R1/R2).
// Embedding: one ds_read_b128 per head from float4-padded LDS rows.

#define HH   20
#define NEX  13
#define PIN(x) asm volatile("" : "+v"(x))

__global__ __launch_bounds__(256, 4) void airfit_kernel(
    const int*   __restrict__ e,   const float* __restrict__ f,
    const float* __restrict__ emb, const float* __restrict__ Wf,
    const float* __restrict__ bf,  const float* __restrict__ W1,
    const float* __restrict__ b1,  const float* __restrict__ W2,
    const float* __restrict__ b2,  const float* __restrict__ Wo,
    const float* __restrict__ bo,  float* __restrict__ out, int B)
{
    __shared__ float4 s_emb[NEX];          // rows padded to 4 floats
    if (threadIdx.x < NEX) {
        int r = threadIdx.x;
        s_emb[r] = make_float4(emb[3 * r + 0], emb[3 * r + 1],
                               emb[3 * r + 2], 0.0f);
    }
    __syncthreads();

    int b = blockIdx.x * 256 + threadIdx.x;
    if (b >= B) return;

    const int4*   ep = reinterpret_cast<const int4*>(e + (size_t)b * HH);
    const float4* fp = reinterpret_cast<const float4*>(f + (size_t)b * (HH * 3));

    // ---- issue all 20 row loads back-to-back ----
    int4   i0 = ep[0], i1 = ep[1], i2 = ep[2], i3 = ep[3], i4 = ep[4];
    float4 f0 = fp[0],  f1 = fp[1],  f2 = fp[2],  f3 = fp[3],  f4 = fp[4];
    float4 f5 = fp[5],  f6 = fp[6],  f7 = fp[7],  f8 = fp[8],  f9 = fp[9];
    float4 f10 = fp[10], f11 = fp[11], f12 = fp[12], f13 = fp[13], f14 = fp[14];

    int er[HH] = { i0.x, i0.y, i0.z, i0.w,  i1.x, i1.y, i1.z, i1.w,
                   i2.x, i2.y, i2.z, i2.w,  i3.x, i3.y, i3.z, i3.w,
                   i4.x, i4.y, i4.z, i4.w };
    float fr[HH * 3] = {
        f0.x, f0.y, f0.z, f0.w,   f1.x, f1.y, f1.z, f1.w,
        f2.x, f2.y, f2.z, f2.w,   f3.x, f3.y, f3.z, f3.w,
        f4.x, f4.y, f4.z, f4.w,   f5.x, f5.y, f5.z, f5.w,
        f6.x, f6.y, f6.z, f6.w,   f7.x, f7.y, f7.z, f7.w,
        f8.x, f8.y, f8.z, f8.w,   f9.x, f9.y, f9.z, f9.w,
        f10.x, f10.y, f10.z, f10.w,  f11.x, f11.y, f11.z, f11.w,
        f12.x, f12.y, f12.z, f12.w,  f13.x, f13.y, f13.z, f13.w,
        f14.x, f14.y, f14.z, f14.w };

    // ---- pin every scalar into a VGPR: compiler cannot rematerialize ----
#pragma unroll
    for (int i = 0; i < HH; ++i)     PIN(er[i]);
#pragma unroll
    for (int i = 0; i < HH * 3; ++i) PIN(fr[i]);

    float acc = bo[0];

#pragma unroll
    for (int h = 0; h < HH; ++h) {
        // embedding gather: one ds_read_b128 (rows are float4)
        float4 ev = s_emb[er[h]];

        float xv[8];
        xv[0] = ev.x; xv[1] = ev.y; xv[2] = ev.z;

        // features Linear 3->5 (Wf stored (in,out))
        float g0 = fr[h * 3 + 0], g1 = fr[h * 3 + 1], g2 = fr[h * 3 + 2];
#pragma unroll
        for (int o = 0; o < 5; ++o) {
            float a = bf[o];
            a = fmaf(g0, Wf[0 * 5 + o], a);
            a = fmaf(g1, Wf[1 * 5 + o], a);
            a = fmaf(g2, Wf[2 * 5 + o], a);
            xv[3 + o] = a;
        }

        // head MLP 8->10, leaky_relu, dot with W2 -> scalar
        float hacc = b2[h];
#pragma unroll
        for (int o = 0; o < 10; ++o) {
            float a = b1[h * 10 + o];
#pragma unroll
            for (int i = 0; i < 8; ++i)
                a = fmaf(xv[i], W1[(h * 8 + i) * 10 + o], a);
            a = fmaxf(a, 0.01f * a);               // leaky_relu, slope .01
            hacc = fmaf(a, W2[h * 10 + o], hacc);
        }

        // softplus = logaddexp(x, 0) = max(x,0) + log1p(exp(-|x|))
        float sp = fmaxf(hacc, 0.0f) + __logf(1.0f + __expf(-fabsf(hacc)));
        acc = fmaf(sp, Wo[h], acc);
    }

    out[b] = acc;
}

extern "C" void kernel_launch(void* const* d_in, const int* in_sizes, int n_in,
                              void* d_out, int out_size, void* d_ws, size_t ws_size,
                              hipStream_t stream) {
    const int*   e   = (const int*)  d_in[0];
    const float* f   = (const float*)d_in[1];
    const float* emb = (const float*)d_in[2];
    const float* Wf  = (const float*)d_in[3];
    const float* bf  = (const float*)d_in[4];
    const float* W1  = (const float*)d_in[5];
    const float* b1  = (const float*)d_in[6];
    const float* W2  = (const float*)d_in[7];
    const float* b2  = (const float*)d_in[8];
    const float* Wo  = (const float*)d_in[9];
    const float* bo  = (const float*)d_in[10];
    float* out = (float*)d_out;

    int B = in_sizes[0] / HH;          // e is (B, 20)
    int blocks = (B + 255) / 256;
    airfit_kernel<<<blocks, 256, 0, stream>>>(e, f, emb, Wf, bf, W1, b1,
                                              W2, b2, Wo, bo, out, B);
}

// Round 4
// 269.289 us; speedup vs baseline: 1.2376x; 1.2376x over previous
//
#include <hip/hip_runtime.h>

// AirFitMultiHeadDNN — R4.
// R1-R3 lesson: one-thread-per-item needs 80 live input values; the compiler
// refuses (VGPR 32-52) and either rematerializes global loads (R1/R2: 2x
// FETCH, 3x VALU) or emits a serial copy chain (R3: VALU 77%, dur worse).
// Fix the STRUCTURE: 5 lanes per item, 4 heads per lane.
//   block = 320 threads = 5 waves x 64 items
//   wave j, lane i  ->  item (blockIdx*64+i), heads [4j, 4j+4)
//   per-thread inputs: one int4 + three float4 (16B-aligned slices of the
//   item row; the 5 waves cover complementary slices of the same lines).
// Head-group j is wave-uniform; switch on readfirstlane(j) dispatches a
// compile-time-J template so all weight indices are constants -> s_load /
// SGPR path (SGPR=112 in R1-R3 proves this works). Partials reduced via LDS.

#define HH   20
#define NEX  13

__device__ __forceinline__ float softplus_fast(float x) {
    // logaddexp(x, 0) = max(x,0) + log1p(exp(-|x|))
    return fmaxf(x, 0.0f) + __logf(1.0f + __expf(-fabsf(x)));
}

template<int J>
__device__ __forceinline__ float head_group(
    int4 iv, float4 fa, float4 fb, float4 fc,
    const float4* __restrict__ s_emb,
    const float* __restrict__ Wf, const float* __restrict__ bf,
    const float* __restrict__ W1, const float* __restrict__ b1,
    const float* __restrict__ W2, const float* __restrict__ b2,
    const float* __restrict__ Wo)
{
    int   ii[4]  = { iv.x, iv.y, iv.z, iv.w };
    float ff[12] = { fa.x, fa.y, fa.z, fa.w,
                     fb.x, fb.y, fb.z, fb.w,
                     fc.x, fc.y, fc.z, fc.w };
    float partial = 0.0f;

#pragma unroll
    for (int t = 0; t < 4; ++t) {
        const int h = 4 * J + t;               // compile-time constant
        float4 ev = s_emb[ii[t]];              // one ds_read_b128

        float xv[8];
        xv[0] = ev.x; xv[1] = ev.y; xv[2] = ev.z;

        float g0 = ff[3 * t + 0], g1 = ff[3 * t + 1], g2 = ff[3 * t + 2];
#pragma unroll
        for (int o = 0; o < 5; ++o) {          // features Linear 3->5
            float a = bf[o];
            a = fmaf(g0, Wf[0 * 5 + o], a);
            a = fmaf(g1, Wf[1 * 5 + o], a);
            a = fmaf(g2, Wf[2 * 5 + o], a);
            xv[3 + o] = a;
        }

        float hacc = b2[h];
#pragma unroll
        for (int o = 0; o < 10; ++o) {         // head MLP 8->10 + leaky + dot
            float a = b1[h * 10 + o];
#pragma unroll
            for (int k = 0; k < 8; ++k)
                a = fmaf(xv[k], W1[(h * 8 + k) * 10 + o], a);
            a = fmaxf(a, 0.01f * a);
            hacc = fmaf(a, W2[h * 10 + o], hacc);
        }

        partial = fmaf(softplus_fast(hacc), Wo[h], partial);
    }
    return partial;
}

__global__ __launch_bounds__(320, 6) void airfit_kernel(
    const int*   __restrict__ e,   const float* __restrict__ f,
    const float* __restrict__ emb, const float* __restrict__ Wf,
    const float* __restrict__ bf,  const float* __restrict__ W1,
    const float* __restrict__ b1,  const float* __restrict__ W2,
    const float* __restrict__ b2,  const float* __restrict__ Wo,
    const float* __restrict__ bo,  float* __restrict__ out, int B)
{
    __shared__ float4 s_emb[NEX];          // emb rows padded to float4
    __shared__ float  s_part[5][64];       // per-(group,item) partial sums

    if (threadIdx.x < NEX) {
        int r = threadIdx.x;
        s_emb[r] = make_float4(emb[3 * r + 0], emb[3 * r + 1],
                               emb[3 * r + 2], 0.0f);
    }
    __syncthreads();

    const int i    = threadIdx.x & 63;     // item within block
    const int jj   = threadIdx.x >> 6;     // head group (wave-uniform)
    const int item = blockIdx.x * 64 + i;

    if (item < B) {
        // this lane's aligned slices of the item row
        int4 iv = *(reinterpret_cast<const int4*>(e + (size_t)item * HH) + jj);
        const float4* fp =
            reinterpret_cast<const float4*>(f + (size_t)item * (HH * 3)) + 3 * jj;
        float4 fa = fp[0], fb = fp[1], fc = fp[2];

        const int j = __builtin_amdgcn_readfirstlane(jj);  // scalar branch
        float partial;
        switch (j) {
        case 0:  partial = head_group<0>(iv, fa, fb, fc, s_emb, Wf, bf, W1, b1, W2, b2, Wo); break;
        case 1:  partial = head_group<1>(iv, fa, fb, fc, s_emb, Wf, bf, W1, b1, W2, b2, Wo); break;
        case 2:  partial = head_group<2>(iv, fa, fb, fc, s_emb, Wf, bf, W1, b1, W2, b2, Wo); break;
        case 3:  partial = head_group<3>(iv, fa, fb, fc, s_emb, Wf, bf, W1, b1, W2, b2, Wo); break;
        default: partial = head_group<4>(iv, fa, fb, fc, s_emb, Wf, bf, W1, b1, W2, b2, Wo); break;
        }
        s_part[jj][i] = partial;
    }
    __syncthreads();

    if (jj == 0 && item < B) {
        float r = bo[0] + s_part[0][i] + s_part[1][i] + s_part[2][i]
                        + s_part[3][i] + s_part[4][i];
        out[item] = r;
    }
}

extern "C" void kernel_launch(void* const* d_in, const int* in_sizes, int n_in,
                              void* d_out, int out_size, void* d_ws, size_t ws_size,
                              hipStream_t stream) {
    const int*   e   = (const int*)  d_in[0];
    const float* f   = (const float*)d_in[1];
    const float* emb = (const float*)d_in[2];
    const float* Wf  = (const float*)d_in[3];
    const float* bf  = (const float*)d_in[4];
    const float* W1  = (const float*)d_in[5];
    const float* b1  = (const float*)d_in[6];
    const float* W2  = (const float*)d_in[7];
    const float* b2  = (const float*)d_in[8];
    const float* Wo  = (const float*)d_in[9];
    const float* bo  = (const float*)d_in[10];
    float* out = (float*)d_out;

    int B = in_sizes[0] / HH;              // e is (B, 20)
    int blocks = (B + 63) / 64;            // 64 items per 320-thread block
    airfit_kernel<<<blocks, 320, 0, stream>>>(e, f, emb, Wf, bf, W1, b1,
                                              W2, b2, Wo, bo, out, B);
}